// Round 5
// baseline (543.966 us; speedup 1.0000x reference)
//
#include <hip/hip_runtime.h>

// RNNNet: 7-layer tanh RNN, N=65536, T=28, V=28, H=64, 10-class head.
// Fully fused, no HBM intermediates. 512 thr (8 waves)/block, wave owns 16 seqs.
// R5: identical to R4 except __launch_bounds__(512,2).
//     Empirical launch_bounds model (this compiler): 2nd arg acts as BLOCKS/CU:
//       (512,1)->cap 256 (got 128), (512,2)->128, (512,4)->64 (R4: spilled,
//       WRITE_SIZE 880MB, dur 499us). 128 VGPR holds this frame with 0 spill
//       (R2 evidence); LDS 69.4KB also allows 2 blocks/CU -> 16 waves/CU.
// GEMMs via mfma_f32_16x16x32_bf16, swapped operands: D[j][s] = W x h^T.

namespace {

typedef __attribute__((ext_vector_type(8))) short bf16x8;
typedef __attribute__((ext_vector_type(4))) float f32x4;

constexpr int TC       = 2;                 // timesteps per chunk
constexpr int NCH      = 14;                // 28 / TC
constexpr int SLAB_W   = TC * 2048;         // per-wave slab: TC*16s*64k*2B
constexpr int SCR      = 8 * SLAB_W;        // 32768: carry scratch rows, 8*2KB
constexpr int WST      = SCR + 8 * 2048;    // 49152: staged Wih (Whh at +8192)
constexpr int WCL      = WST + 16384;       // 65536: Wc padded [16][64] bf16
constexpr int BIA      = WCL + 2048;        // 67584: (bih+bhh)*K f32 [7][64]
constexpr int BCV      = BIA + 1792;        // 69376: bc f32 padded [16]
constexpr int LDS_TOTAL= BCV + 64;          // 69440  (2 blocks/CU: 138880<160K)

constexpr float TANH_K = 2.8853900817779268f;   // 2/ln(2)

// input pre-scaled by 2/ln2: tanh(x) = 1 - 2/(2^a + 1), a = TANH_K*x.
// Saturates correctly at +/-inf of exp2 (no clamp); exp2/rcp are ~1ulp HW ops.
// (R3's poly version had a signed ~5e-5 bias -> coherent drift over 196 steps.)
__device__ __forceinline__ float tanh_pre(float a) {
    float z = __builtin_amdgcn_exp2f(a);
    return fmaf(-2.f, __builtin_amdgcn_rcpf(z + 1.f), 1.f);
}

__device__ __forceinline__ unsigned cvt_pk(float a, float b) {
    unsigned r;                              // r.lo=bf16(a), r.hi=bf16(b), RNE
    asm("v_cvt_pk_bf16_f32 %0, %1, %2" : "=v"(r) : "v"(a), "v"(b));
    return r;
}
__device__ __forceinline__ int4 pack8s(const float* v, float s) {
    return make_int4((int)cvt_pk(v[0] * s, v[1] * s), (int)cvt_pk(v[2] * s, v[3] * s),
                     (int)cvt_pk(v[4] * s, v[5] * s), (int)cvt_pk(v[6] * s, v[7] * s));
}

} // namespace

__global__ void __launch_bounds__(512, 2)   // 2 blocks/CU -> 128 VGPR cap, 0 spill
rnn_fused(const float* __restrict__ x,    const float* __restrict__ Wih0,
          const float* __restrict__ Wih,  const float* __restrict__ Whh,
          const float* __restrict__ bih,  const float* __restrict__ bhh,
          const float* __restrict__ Wc,   const float* __restrict__ bc,
          float* __restrict__ out)
{
    extern __shared__ char smem[];
    const int tid  = threadIdx.x;
    const int lane = tid & 63;
    const int wid  = tid >> 6;          // wave 0..7
    const int sl   = lane & 15;         // s within wave / frag row
    const int g    = lane >> 4;         // lane group 0..3
    const int swzS = (sl & 7) << 4;     // LDS row XOR swizzle
    const int slab0 = wid * SLAB_W;
    const int scr0  = SCR + wid * 2048;
    const int seqbase = blockIdx.x * 128 + wid * 16;

    // loop-invariant swizzled offsets
    const int rd0 = (g * 16) ^ swzS;
    const int rd1 = (64 + g * 16) ^ swzS;
    int wro[4];
#pragma unroll
    for (int jt = 0; jt < 4; ++jt) wro[jt] = (jt * 32 + g * 8) ^ swzS;

    // ---------------- one-time resident staging ----------------
    if (tid < 128) { // Wc zero-padded to [16][64] (UNscaled: no tanh after)
        int c = tid >> 3, k0 = (tid & 7) * 8;
        float v[8];
#pragma unroll
        for (int e = 0; e < 8; ++e) v[e] = (c < 10) ? Wc[c * 64 + k0 + e] : 0.f;
        *(int4*)(smem + WCL + c * 128 + ((k0 * 2) ^ ((c & 7) << 4))) = pack8s(v, 1.f);
    }
    if (tid < 448) *(float*)(smem + BIA + tid * 4) = (bih[tid] + bhh[tid]) * TANH_K;
    if (tid < 16)  *(float*)(smem + BCV + tid * 4) = (tid < 10) ? bc[tid] : 0.f;
    __syncthreads();

    unsigned carry[7][8] = {};   // per-layer h(chunk end), 4 jt * 4 bf16 packed

#pragma unroll 1
    for (int chunk = 0; chunk < NCH; ++chunk) {
        const int t0 = chunk * TC;

        // ---- stage x rows t0..t0+1 into this wave's slab (wave-private) ----
        {
            const int t  = g & 1;
            const int rb = slab0 + t * 2048 + sl * 128;
            if (g < 2) {        // k < 28: load + cvt
                const float* xs = x + (size_t)(seqbase + sl) * 784 + (size_t)(t0 + t) * 28;
#pragma unroll
                for (int q = 0; q < 7; ++q) {
                    float4 v4 = *(const float4*)(xs + q * 4);
                    *(int2*)(smem + rb + ((q * 8) ^ swzS)) =
                        make_int2((int)cvt_pk(v4.x, v4.y), (int)cvt_pk(v4.z, v4.w));
                }
            } else {            // k = 28..63: zero (stale h from prev chunk!)
#pragma unroll
                for (int q = 7; q < 16; ++q)
                    *(int2*)(smem + rb + ((q * 8) ^ swzS)) = make_int2(0, 0);
            }
        }

#pragma unroll 1
        for (int l = 0; l < 7; ++l) {
            // barrier A: all waves done with previous layer (WST readers drained)
            __syncthreads();
            {   // ---- stage this layer's weights (scaled by 2/ln2) ----
                int j = tid >> 3, k0 = (tid & 7) * 8;
                float v[8];
                if (l == 0) {   // Wih0 zero-padded [64][28->64]
#pragma unroll
                    for (int e = 0; e < 8; ++e)
                        v[e] = (k0 + e < 28) ? Wih0[j * 28 + k0 + e] : 0.f;
                } else {
                    const float* src = Wih + (size_t)(l - 1) * 4096 + j * 64 + k0;
                    float4 a4 = *(const float4*)(src);
                    float4 b4 = *(const float4*)(src + 4);
                    v[0]=a4.x; v[1]=a4.y; v[2]=a4.z; v[3]=a4.w;
                    v[4]=b4.x; v[5]=b4.y; v[6]=b4.z; v[7]=b4.w;
                }
                *(int4*)(smem + WST + j * 128 + ((k0 * 2) ^ ((j & 7) << 4))) = pack8s(v, TANH_K);
                const float* srh = Whh + (size_t)l * 4096 + j * 64 + k0;
                float4 a4 = *(const float4*)(srh);
                float4 b4 = *(const float4*)(srh + 4);
                float w[8] = {a4.x, a4.y, a4.z, a4.w, b4.x, b4.y, b4.z, b4.w};
                *(int4*)(smem + WST + 8192 + j * 128 + ((k0 * 2) ^ ((j & 7) << 4))) = pack8s(w, TANH_K);
            }
            __syncthreads();   // barrier B: weights visible

            // ---- hoist W fragments (A-operand: lane&15 = row j) + bias ----
            bf16x8 wihf[4][2], whhf[4][2];
            f32x4  biasr[4];
#pragma unroll
            for (int jt = 0; jt < 4; ++jt) {
                const int rowoff = (jt * 16 + sl) * 128;   // (j&7)==(sl&7)
#pragma unroll
                for (int kf = 0; kf < 2; ++kf) {
                    const int kb = (kf * 64 + g * 16) ^ swzS;
                    wihf[jt][kf] = *(const bf16x8*)(smem + WST + rowoff + kb);
                    whhf[jt][kf] = *(const bf16x8*)(smem + WST + 8192 + rowoff + kb);
                }
                biasr[jt] = *(const f32x4*)(smem + BIA + l * 256 + jt * 64 + g * 16);
            }

            // ---- restore carry (h at t0-1) into scratch row (wave-private) ----
#pragma unroll
            for (int jt = 0; jt < 4; ++jt)
                *(int2*)(smem + scr0 + sl * 128 + wro[jt]) =
                    make_int2((int)carry[l][jt * 2], (int)carry[l][jt * 2 + 1]);

            // ---- time loop (fully unrolled, wave-private, no barriers) ----
#pragma unroll
            for (int tt = 0; tt < TC; ++tt) {
                const int in_base  = slab0 + tt * 2048 + sl * 128;
                const int rec_base = (tt == 0) ? (scr0 + sl * 128)
                                               : (slab0 + (tt - 1) * 2048 + sl * 128);
                bf16x8 bin0 = *(const bf16x8*)(smem + in_base  + rd0);
                bf16x8 bin1 = *(const bf16x8*)(smem + in_base  + rd1);
                bf16x8 br0  = *(const bf16x8*)(smem + rec_base + rd0);
                bf16x8 br1  = *(const bf16x8*)(smem + rec_base + rd1);
#pragma unroll
                for (int jt = 0; jt < 4; ++jt) {
                    f32x4 a = biasr[jt];   // bias as mfma C-in
                    a = __builtin_amdgcn_mfma_f32_16x16x32_bf16(wihf[jt][0], bin0, a, 0, 0, 0);
                    a = __builtin_amdgcn_mfma_f32_16x16x32_bf16(wihf[jt][1], bin1, a, 0, 0, 0);
                    a = __builtin_amdgcn_mfma_f32_16x16x32_bf16(whhf[jt][0], br0, a, 0, 0, 0);
                    a = __builtin_amdgcn_mfma_f32_16x16x32_bf16(whhf[jt][1], br1, a, 0, 0, 0);
                    // D: col = lane&15 = s, rows j = jt*16 + g*4 + r
                    unsigned p0 = cvt_pk(tanh_pre(a[0]), tanh_pre(a[1]));
                    unsigned p1 = cvt_pk(tanh_pre(a[2]), tanh_pre(a[3]));
                    if (tt == TC - 1) { carry[l][jt * 2] = p0; carry[l][jt * 2 + 1] = p1; }
                    *(int2*)(smem + in_base + wro[jt]) = make_int2((int)p0, (int)p1);
                }
            }
        }
    }

    // ---------------- classifier: out = h6(t=27) @ Wc^T + bc ----------------
    {
        const int in_base = slab0 + (TC - 1) * 2048 + sl * 128;  // t = 27
        bf16x8 b0 = *(const bf16x8*)(smem + in_base + rd0);
        bf16x8 b1 = *(const bf16x8*)(smem + in_base + rd1);
        const int rowoff = sl * 128;                             // A row = class c
        bf16x8 w0 = *(const bf16x8*)(smem + WCL + rowoff + rd0);
        bf16x8 w1 = *(const bf16x8*)(smem + WCL + rowoff + rd1);
        f32x4 o = {0.f, 0.f, 0.f, 0.f};
        o = __builtin_amdgcn_mfma_f32_16x16x32_bf16(w0, b0, o, 0, 0, 0);
        o = __builtin_amdgcn_mfma_f32_16x16x32_bf16(w1, b1, o, 0, 0, 0);
        f32x4 bb = *(const f32x4*)(smem + BCV + g * 16);
#pragma unroll
        for (int r = 0; r < 4; ++r) {
            const int c = g * 4 + r;
            if (c < 10)
                out[(size_t)(seqbase + sl) * 10 + c] = o[r] + bb[r];
        }
    }
}

extern "C" void kernel_launch(void* const* d_in, const int* in_sizes, int n_in,
                              void* d_out, int out_size, void* d_ws, size_t ws_size,
                              hipStream_t stream) {
    (void)in_sizes; (void)n_in; (void)d_ws; (void)ws_size; (void)out_size;
    hipFuncSetAttribute((const void*)rnn_fused,
                        hipFuncAttributeMaxDynamicSharedMemorySize, LDS_TOTAL);
    rnn_fused<<<dim3(512), dim3(512), LDS_TOTAL, stream>>>(
        (const float*)d_in[0], (const float*)d_in[1], (const float*)d_in[2],
        (const float*)d_in[3], (const float*)d_in[4], (const float*)d_in[5],
        (const float*)d_in[6], (const float*)d_in[7], (float*)d_out);
}

// Round 6
// 432.573 us; speedup vs baseline: 1.2575x; 1.2575x over previous
//
#include <hip/hip_runtime.h>

// RNNNet: 7-layer tanh RNN, N=65536, T=28, V=28, H=64, 10-class head.
// Fully fused, no HBM intermediates. 512 thr (8 waves)/block, wave owns 16 seqs.
// R6: TC=2 chunks (LDS 69.4KB -> 2 blocks/CU by LDS) + l-loop FULLY UNROLLED.
//     R4/R5's 0.9GB scratch traffic was NOT launch_bounds: carry[7][8] indexed
//     by runtime l (l-loop '#pragma unroll 1' since R3) went to local memory
//     (rule: runtime-indexed arrays -> scratch). Full unroll -> carry in regs.
//     launch_bounds(512,1): R2 proved the compiler naturally picks 128 VGPR
//     (zero spill) for this per-layer body when uncapped.
// GEMMs via mfma_f32_16x16x32_bf16, swapped operands: D[j][s] = W x h^T.

namespace {

typedef __attribute__((ext_vector_type(8))) short bf16x8;
typedef __attribute__((ext_vector_type(4))) float f32x4;

constexpr int TC       = 2;                 // timesteps per chunk
constexpr int NCH      = 14;                // 28 / TC
constexpr int SLAB_W   = TC * 2048;         // per-wave slab: TC*16s*64k*2B
constexpr int SCR      = 8 * SLAB_W;        // 32768: carry scratch rows, 8*2KB
constexpr int WST      = SCR + 8 * 2048;    // 49152: staged Wih (Whh at +8192)
constexpr int WCL      = WST + 16384;       // 65536: Wc padded [16][64] bf16
constexpr int BIA      = WCL + 2048;        // 67584: (bih+bhh)*K f32 [7][64]
constexpr int BCV      = BIA + 1792;        // 69376: bc f32 padded [16]
constexpr int LDS_TOTAL= BCV + 64;          // 69440  (2 blocks/CU: 138880<160K)

constexpr float TANH_K = 2.8853900817779268f;   // 2/ln(2)

// input pre-scaled by 2/ln2: tanh(x) = 1 - 2/(2^a + 1), a = TANH_K*x.
// Saturates correctly at +/-inf of exp2 (no clamp); exp2/rcp are ~1ulp HW ops.
// (Deg-5 poly variant had a signed ~5e-5 bias -> coherent drift over 196 steps
//  -> failed threshold by 0.07%. Keep the 1-ulp form.)
__device__ __forceinline__ float tanh_pre(float a) {
    float z = __builtin_amdgcn_exp2f(a);
    return fmaf(-2.f, __builtin_amdgcn_rcpf(z + 1.f), 1.f);
}

__device__ __forceinline__ unsigned cvt_pk(float a, float b) {
    unsigned r;                              // r.lo=bf16(a), r.hi=bf16(b), RNE
    asm("v_cvt_pk_bf16_f32 %0, %1, %2" : "=v"(r) : "v"(a), "v"(b));
    return r;
}
__device__ __forceinline__ int4 pack8s(const float* v, float s) {
    return make_int4((int)cvt_pk(v[0] * s, v[1] * s), (int)cvt_pk(v[2] * s, v[3] * s),
                     (int)cvt_pk(v[4] * s, v[5] * s), (int)cvt_pk(v[6] * s, v[7] * s));
}

} // namespace

__global__ void __launch_bounds__(512, 1)   // uncapped; compiler targets 128 (R2)
rnn_fused(const float* __restrict__ x,    const float* __restrict__ Wih0,
          const float* __restrict__ Wih,  const float* __restrict__ Whh,
          const float* __restrict__ bih,  const float* __restrict__ bhh,
          const float* __restrict__ Wc,   const float* __restrict__ bc,
          float* __restrict__ out)
{
    extern __shared__ char smem[];
    const int tid  = threadIdx.x;
    const int lane = tid & 63;
    const int wid  = tid >> 6;          // wave 0..7
    const int sl   = lane & 15;         // s within wave / frag row
    const int g    = lane >> 4;         // lane group 0..3
    const int swzS = (sl & 7) << 4;     // LDS row XOR swizzle
    const int slab0 = wid * SLAB_W;
    const int scr0  = SCR + wid * 2048;
    const int seqbase = blockIdx.x * 128 + wid * 16;

    // loop-invariant swizzled offsets
    const int rd0 = (g * 16) ^ swzS;
    const int rd1 = (64 + g * 16) ^ swzS;
    int wro[4];
#pragma unroll
    for (int jt = 0; jt < 4; ++jt) wro[jt] = (jt * 32 + g * 8) ^ swzS;

    // ---------------- one-time resident staging ----------------
    if (tid < 128) { // Wc zero-padded to [16][64] (UNscaled: no tanh after)
        int c = tid >> 3, k0 = (tid & 7) * 8;
        float v[8];
#pragma unroll
        for (int e = 0; e < 8; ++e) v[e] = (c < 10) ? Wc[c * 64 + k0 + e] : 0.f;
        *(int4*)(smem + WCL + c * 128 + ((k0 * 2) ^ ((c & 7) << 4))) = pack8s(v, 1.f);
    }
    if (tid < 448) *(float*)(smem + BIA + tid * 4) = (bih[tid] + bhh[tid]) * TANH_K;
    if (tid < 16)  *(float*)(smem + BCV + tid * 4) = (tid < 10) ? bc[tid] : 0.f;
    __syncthreads();

    unsigned carry[7][8] = {};   // per-layer h(chunk end); ALL indices static!

#pragma unroll 1
    for (int chunk = 0; chunk < NCH; ++chunk) {
        const int t0 = chunk * TC;

        // ---- stage x rows t0..t0+1 into this wave's slab (wave-private) ----
        {
            const int t  = g & 1;
            const int rb = slab0 + t * 2048 + sl * 128;
            if (g < 2) {        // k < 28: load + cvt
                const float* xs = x + (size_t)(seqbase + sl) * 784 + (size_t)(t0 + t) * 28;
#pragma unroll
                for (int q = 0; q < 7; ++q) {
                    float4 v4 = *(const float4*)(xs + q * 4);
                    *(int2*)(smem + rb + ((q * 8) ^ swzS)) =
                        make_int2((int)cvt_pk(v4.x, v4.y), (int)cvt_pk(v4.z, v4.w));
                }
            } else {            // k = 28..63: zero (stale h from prev chunk!)
#pragma unroll
                for (int q = 7; q < 16; ++q)
                    *(int2*)(smem + rb + ((q * 8) ^ swzS)) = make_int2(0, 0);
            }
        }

#pragma unroll              // FULL unroll: carry[l] must be compile-time indexed
        for (int l = 0; l < 7; ++l) {
            // barrier A: all waves done with previous layer (WST readers drained)
            __syncthreads();
            {   // ---- stage this layer's weights (scaled by 2/ln2) ----
                int j = tid >> 3, k0 = (tid & 7) * 8;
                float v[8];
                if (l == 0) {   // Wih0 zero-padded [64][28->64]
#pragma unroll
                    for (int e = 0; e < 8; ++e)
                        v[e] = (k0 + e < 28) ? Wih0[j * 28 + k0 + e] : 0.f;
                } else {
                    const float* src = Wih + (size_t)(l - 1) * 4096 + j * 64 + k0;
                    float4 a4 = *(const float4*)(src);
                    float4 b4 = *(const float4*)(src + 4);
                    v[0]=a4.x; v[1]=a4.y; v[2]=a4.z; v[3]=a4.w;
                    v[4]=b4.x; v[5]=b4.y; v[6]=b4.z; v[7]=b4.w;
                }
                *(int4*)(smem + WST + j * 128 + ((k0 * 2) ^ ((j & 7) << 4))) = pack8s(v, TANH_K);
                const float* srh = Whh + (size_t)l * 4096 + j * 64 + k0;
                float4 a4 = *(const float4*)(srh);
                float4 b4 = *(const float4*)(srh + 4);
                float w[8] = {a4.x, a4.y, a4.z, a4.w, b4.x, b4.y, b4.z, b4.w};
                *(int4*)(smem + WST + 8192 + j * 128 + ((k0 * 2) ^ ((j & 7) << 4))) = pack8s(w, TANH_K);
            }
            __syncthreads();   // barrier B: weights visible

            // ---- hoist W fragments (A-operand: lane&15 = row j) + bias ----
            bf16x8 wihf[4][2], whhf[4][2];
            f32x4  biasr[4];
#pragma unroll
            for (int jt = 0; jt < 4; ++jt) {
                const int rowoff = (jt * 16 + sl) * 128;   // (j&7)==(sl&7)
#pragma unroll
                for (int kf = 0; kf < 2; ++kf) {
                    const int kb = (kf * 64 + g * 16) ^ swzS;
                    wihf[jt][kf] = *(const bf16x8*)(smem + WST + rowoff + kb);
                    whhf[jt][kf] = *(const bf16x8*)(smem + WST + 8192 + rowoff + kb);
                }
                biasr[jt] = *(const f32x4*)(smem + BIA + l * 256 + jt * 64 + g * 16);
            }

            // ---- restore carry (h at t0-1) into scratch row (wave-private) ----
#pragma unroll
            for (int jt = 0; jt < 4; ++jt)
                *(int2*)(smem + scr0 + sl * 128 + wro[jt]) =
                    make_int2((int)carry[l][jt * 2], (int)carry[l][jt * 2 + 1]);

            // ---- time loop (fully unrolled, wave-private, no barriers) ----
#pragma unroll
            for (int tt = 0; tt < TC; ++tt) {
                const int in_base  = slab0 + tt * 2048 + sl * 128;
                const int rec_base = (tt == 0) ? (scr0 + sl * 128)
                                               : (slab0 + (tt - 1) * 2048 + sl * 128);
                bf16x8 bin0 = *(const bf16x8*)(smem + in_base  + rd0);
                bf16x8 bin1 = *(const bf16x8*)(smem + in_base  + rd1);
                bf16x8 br0  = *(const bf16x8*)(smem + rec_base + rd0);
                bf16x8 br1  = *(const bf16x8*)(smem + rec_base + rd1);
#pragma unroll
                for (int jt = 0; jt < 4; ++jt) {
                    f32x4 a = biasr[jt];   // bias as mfma C-in
                    a = __builtin_amdgcn_mfma_f32_16x16x32_bf16(wihf[jt][0], bin0, a, 0, 0, 0);
                    a = __builtin_amdgcn_mfma_f32_16x16x32_bf16(wihf[jt][1], bin1, a, 0, 0, 0);
                    a = __builtin_amdgcn_mfma_f32_16x16x32_bf16(whhf[jt][0], br0, a, 0, 0, 0);
                    a = __builtin_amdgcn_mfma_f32_16x16x32_bf16(whhf[jt][1], br1, a, 0, 0, 0);
                    // D: col = lane&15 = s, rows j = jt*16 + g*4 + r
                    unsigned p0 = cvt_pk(tanh_pre(a[0]), tanh_pre(a[1]));
                    unsigned p1 = cvt_pk(tanh_pre(a[2]), tanh_pre(a[3]));
                    if (tt == TC - 1) { carry[l][jt * 2] = p0; carry[l][jt * 2 + 1] = p1; }
                    *(int2*)(smem + in_base + wro[jt]) = make_int2((int)p0, (int)p1);
                }
            }
        }
    }

    // ---------------- classifier: out = h6(t=27) @ Wc^T + bc ----------------
    {
        const int in_base = slab0 + (TC - 1) * 2048 + sl * 128;  // t = 27
        bf16x8 b0 = *(const bf16x8*)(smem + in_base + rd0);
        bf16x8 b1 = *(const bf16x8*)(smem + in_base + rd1);
        const int rowoff = sl * 128;                             // A row = class c
        bf16x8 w0 = *(const bf16x8*)(smem + WCL + rowoff + rd0);
        bf16x8 w1 = *(const bf16x8*)(smem + WCL + rowoff + rd1);
        f32x4 o = {0.f, 0.f, 0.f, 0.f};
        o = __builtin_amdgcn_mfma_f32_16x16x32_bf16(w0, b0, o, 0, 0, 0);
        o = __builtin_amdgcn_mfma_f32_16x16x32_bf16(w1, b1, o, 0, 0, 0);
        f32x4 bb = *(const f32x4*)(smem + BCV + g * 16);
#pragma unroll
        for (int r = 0; r < 4; ++r) {
            const int c = g * 4 + r;
            if (c < 10)
                out[(size_t)(seqbase + sl) * 10 + c] = o[r] + bb[r];
        }
    }
}

extern "C" void kernel_launch(void* const* d_in, const int* in_sizes, int n_in,
                              void* d_out, int out_size, void* d_ws, size_t ws_size,
                              hipStream_t stream) {
    (void)in_sizes; (void)n_in; (void)d_ws; (void)ws_size; (void)out_size;
    hipFuncSetAttribute((const void*)rnn_fused,
                        hipFuncAttributeMaxDynamicSharedMemorySize, LDS_TOTAL);
    rnn_fused<<<dim3(512), dim3(512), LDS_TOTAL, stream>>>(
        (const float*)d_in[0], (const float*)d_in[1], (const float*)d_in[2],
        (const float*)d_in[3], (const float*)d_in[4], (const float*)d_in[5],
        (const float*)d_in[6], (const float*)d_in[7], (float*)d_out);
}

// Round 7
// 268.623 us; speedup vs baseline: 2.0250x; 1.6103x over previous
//
#include <hip/hip_runtime.h>

// RNNNet: 7-layer tanh RNN, N=65536, T=28, V=28, H=64, 10-class head.
// R7: time-outer / layer-inner, BARRIER-FREE main loop.
//  - ALL weights resident in LDS (7 x 16KB, staged once; zero restaging).
//  - h flows layer-to-layer in registers (B-frag ring hb[7], static indices).
//  - per-wave 2KB scratch row only for D->B relayout (in-order DS, no barrier).
//  - x loaded per-lane directly from global as its own B-fragment (no staging).
//  - time-PAIR per weight-fragment load: halves weight ds_read traffic.
//  Numerically bit-identical to R2 (same MFMA order / rounding points).
// GEMMs via mfma_f32_16x16x32_bf16, swapped operands: D[j][s] = W x h^T.

namespace {

typedef __attribute__((ext_vector_type(8))) short bf16x8;
typedef __attribute__((ext_vector_type(4))) float f32x4;
typedef __attribute__((ext_vector_type(4))) unsigned u32x4;

constexpr int WST = 0;                  // 7 layers x (ih 8KB + hh 8KB) bf16 swz
constexpr int SCR = 7 * 16384;          // 114688: 8 wave-private relayout rows
constexpr int WCL = SCR + 8 * 2048;     // 131072: Wc padded [16][64] bf16
constexpr int BIA = WCL + 2048;         // 133120: (bih+bhh)*K f32 [7][64]
constexpr int BCV = BIA + 1792;         // 134912: bc f32 padded [16]
constexpr int LDS_TOTAL = BCV + 64;     // 134976 (< 163840, 1 block/CU)

constexpr float TANH_K = 2.8853900817779268f;   // 2/ln(2)

// input pre-scaled by 2/ln2: tanh(x) = 1 - 2/(2^a + 1). 1-ulp HW ops, no bias.
__device__ __forceinline__ float tanh_pre(float a) {
    float z = __builtin_amdgcn_exp2f(a);
    return fmaf(-2.f, __builtin_amdgcn_rcpf(z + 1.f), 1.f);
}
__device__ __forceinline__ unsigned cvt_pk(float a, float b) {
    unsigned r;                              // lo=bf16(a), hi=bf16(b), RNE
    asm("v_cvt_pk_bf16_f32 %0, %1, %2" : "=v"(r) : "v"(a), "v"(b));
    return r;
}
__device__ __forceinline__ int4 pack8s(const float* v, float s) {
    return make_int4((int)cvt_pk(v[0] * s, v[1] * s), (int)cvt_pk(v[2] * s, v[3] * s),
                     (int)cvt_pk(v[4] * s, v[5] * s), (int)cvt_pk(v[6] * s, v[7] * s));
}
__device__ __forceinline__ bf16x8 pk8(float4 a, float4 b) {
    u32x4 t;
    t[0] = cvt_pk(a.x, a.y); t[1] = cvt_pk(a.z, a.w);
    t[2] = cvt_pk(b.x, b.y); t[3] = cvt_pk(b.z, b.w);
    return __builtin_bit_cast(bf16x8, t);
}

} // namespace

__global__ void __launch_bounds__(512, 1)
rnn_fused(const float* __restrict__ x,    const float* __restrict__ Wih0,
          const float* __restrict__ Wih,  const float* __restrict__ Whh,
          const float* __restrict__ bih,  const float* __restrict__ bhh,
          const float* __restrict__ Wc,   const float* __restrict__ bc,
          float* __restrict__ out)
{
    extern __shared__ char smem[];
    const int tid  = threadIdx.x;
    const int lane = tid & 63;
    const int wid  = tid >> 6;          // wave 0..7
    const int sl   = lane & 15;         // seq-in-wave / frag row
    const int g    = lane >> 4;         // lane group 0..3
    const int swzS = (sl & 7) << 4;     // LDS row XOR swizzle
    const int seqbase = blockIdx.x * 128 + wid * 16;

    const int rd0 = (g * 16) ^ swzS;        // B-frag k = g*8..g*8+7
    const int rd1 = (64 + g * 16) ^ swzS;   // B-frag k = 32+g*8..
    int wro[4];
#pragma unroll
    for (int jt = 0; jt < 4; ++jt) wro[jt] = (jt * 32 + g * 8) ^ swzS;
    const int scrw = SCR + wid * 2048 + sl * 128;   // wave-private relayout row

    // ---------------- one-time staging: ALL weights -> LDS ----------------
    {
        const int j = tid >> 3, k0 = (tid & 7) * 8;
        const int wz = (k0 * 2) ^ ((j & 7) << 4);
#pragma unroll
        for (int l = 0; l < 7; ++l) {
            float v[8];
            if (l == 0) {   // Wih0 zero-padded [64][28->64]
#pragma unroll
                for (int e = 0; e < 8; ++e)
                    v[e] = (k0 + e < 28) ? Wih0[j * 28 + k0 + e] : 0.f;
            } else {
                const float* src = Wih + (size_t)(l - 1) * 4096 + j * 64 + k0;
                float4 a4 = *(const float4*)(src);
                float4 b4 = *(const float4*)(src + 4);
                v[0]=a4.x; v[1]=a4.y; v[2]=a4.z; v[3]=a4.w;
                v[4]=b4.x; v[5]=b4.y; v[6]=b4.z; v[7]=b4.w;
            }
            *(int4*)(smem + WST + l * 16384 + j * 128 + wz) = pack8s(v, TANH_K);
            const float* srh = Whh + (size_t)l * 4096 + j * 64 + k0;
            float4 a4 = *(const float4*)(srh);
            float4 b4 = *(const float4*)(srh + 4);
            float w[8] = {a4.x, a4.y, a4.z, a4.w, b4.x, b4.y, b4.z, b4.w};
            *(int4*)(smem + WST + l * 16384 + 8192 + j * 128 + wz) = pack8s(w, TANH_K);
        }
    }
    if (tid < 128) { // Wc zero-padded [16][64] (UNscaled: no tanh after)
        int c = tid >> 3, k0 = (tid & 7) * 8;
        float v[8];
#pragma unroll
        for (int e = 0; e < 8; ++e) v[e] = (c < 10) ? Wc[c * 64 + k0 + e] : 0.f;
        *(int4*)(smem + WCL + c * 128 + ((k0 * 2) ^ ((c & 7) << 4))) = pack8s(v, 1.f);
    }
    if (tid < 448) *(float*)(smem + BIA + tid * 4) = (bih[tid] + bhh[tid]) * TANH_K;
    if (tid < 16)  *(float*)(smem + BCV + tid * 4) = (tid < 10) ? bc[tid] : 0.f;
    __syncthreads();    // the ONLY barrier; main loop is wave-independent

    // ---------------- main loop: time-pair outer, layer inner ----------------
    const bf16x8 zf = {};
    bf16x8 hb0[7], hb1[7];          // h(l, t-1) B-frag pair (static indices!)
#pragma unroll
    for (int l = 0; l < 7; ++l) { hb0[l] = zf; hb1[l] = zf; }

    const float* xr = x + (size_t)(seqbase + sl) * 784 + g * 8;

#pragma unroll 1
    for (int tp = 0; tp < 14; ++tp) {
        // x B-frags for t=2tp and t=2tp+1, loaded straight from global.
        // g=3 upper half (k=28..31) forced zero: stays in-bounds & kills pad.
        const float* p0 = xr + tp * 56;
        float4 a0 = *(const float4*)(p0);
        float4 a1 = (g < 3) ? *(const float4*)(p0 + 4) : make_float4(0.f, 0.f, 0.f, 0.f);
        float4 b0 = *(const float4*)(p0 + 28);
        float4 b1 = (g < 3) ? *(const float4*)(p0 + 32) : make_float4(0.f, 0.f, 0.f, 0.f);
        const bf16x8 xt = pk8(a0, a1);
        const bf16x8 xu = pk8(b0, b1);

        bf16x8 it0, it1, iu0, iu1;  // layer-(l-1) output frags, times t / t+1

#pragma unroll                      // FULL unroll: hb[l] + LDS offsets static
        for (int l = 0; l < 7; ++l) {
            const int wb = WST + l * 16384;
            bf16x8 wi0[4], wi1[4], wh0[4], wh1[4];
            f32x4  bs[4];
#pragma unroll
            for (int jt = 0; jt < 4; ++jt) {
                const int ro = wb + (jt * 16 + sl) * 128;
                wi0[jt] = *(const bf16x8*)(smem + ro + rd0);
                if (l) wi1[jt] = *(const bf16x8*)(smem + ro + rd1);  // l=0: k>=32 all zero, skip
                wh0[jt] = *(const bf16x8*)(smem + ro + 8192 + rd0);
                wh1[jt] = *(const bf16x8*)(smem + ro + 8192 + rd1);
                bs[jt]  = *(const f32x4*)(smem + BIA + l * 256 + jt * 64 + g * 16);
            }
            const bf16x8 i0 = l ? it0 : xt;
            const bf16x8 i1 = l ? it1 : zf;
            // ---- time t ----
#pragma unroll
            for (int jt = 0; jt < 4; ++jt) {
                f32x4 a = bs[jt];   // bias as mfma C-in
                a = __builtin_amdgcn_mfma_f32_16x16x32_bf16(wi0[jt], i0, a, 0, 0, 0);
                if (l) a = __builtin_amdgcn_mfma_f32_16x16x32_bf16(wi1[jt], i1, a, 0, 0, 0);
                a = __builtin_amdgcn_mfma_f32_16x16x32_bf16(wh0[jt], hb0[l], a, 0, 0, 0);
                a = __builtin_amdgcn_mfma_f32_16x16x32_bf16(wh1[jt], hb1[l], a, 0, 0, 0);
                unsigned q0 = cvt_pk(tanh_pre(a[0]), tanh_pre(a[1]));
                unsigned q1 = cvt_pk(tanh_pre(a[2]), tanh_pre(a[3]));
                *(int2*)(smem + scrw + wro[jt]) = make_int2((int)q0, (int)q1);
            }
            const bf16x8 n0 = *(const bf16x8*)(smem + scrw + rd0);  // h(l,t) B-frag
            const bf16x8 n1 = *(const bf16x8*)(smem + scrw + rd1);
            // ---- time t+1 ----
            const bf16x8 j0 = l ? iu0 : xu;
            const bf16x8 j1 = l ? iu1 : zf;
#pragma unroll
            for (int jt = 0; jt < 4; ++jt) {
                f32x4 a = bs[jt];
                a = __builtin_amdgcn_mfma_f32_16x16x32_bf16(wi0[jt], j0, a, 0, 0, 0);
                if (l) a = __builtin_amdgcn_mfma_f32_16x16x32_bf16(wi1[jt], j1, a, 0, 0, 0);
                a = __builtin_amdgcn_mfma_f32_16x16x32_bf16(wh0[jt], n0, a, 0, 0, 0);
                a = __builtin_amdgcn_mfma_f32_16x16x32_bf16(wh1[jt], n1, a, 0, 0, 0);
                unsigned q0 = cvt_pk(tanh_pre(a[0]), tanh_pre(a[1]));
                unsigned q1 = cvt_pk(tanh_pre(a[2]), tanh_pre(a[3]));
                *(int2*)(smem + scrw + wro[jt]) = make_int2((int)q0, (int)q1);
            }
            const bf16x8 m0 = *(const bf16x8*)(smem + scrw + rd0);  // h(l,t+1) B-frag
            const bf16x8 m1 = *(const bf16x8*)(smem + scrw + rd1);
            hb0[l] = m0; hb1[l] = m1;
            it0 = n0; it1 = n1; iu0 = m0; iu1 = m1;
        }
    }

    // ---------------- classifier: out = h6(t=27) @ Wc^T + bc ----------------
    {
        const int ro = WCL + sl * 128;                   // A row = class c = sl
        bf16x8 w0 = *(const bf16x8*)(smem + ro + rd0);
        bf16x8 w1 = *(const bf16x8*)(smem + ro + rd1);
        f32x4 o = {0.f, 0.f, 0.f, 0.f};
        o = __builtin_amdgcn_mfma_f32_16x16x32_bf16(w0, hb0[6], o, 0, 0, 0);
        o = __builtin_amdgcn_mfma_f32_16x16x32_bf16(w1, hb1[6], o, 0, 0, 0);
        f32x4 bb = *(const f32x4*)(smem + BCV + g * 16);
#pragma unroll
        for (int r = 0; r < 4; ++r) {
            const int c = g * 4 + r;
            if (c < 10)
                out[(size_t)(seqbase + sl) * 10 + c] = o[r] + bb[r];
        }
    }
}

extern "C" void kernel_launch(void* const* d_in, const int* in_sizes, int n_in,
                              void* d_out, int out_size, void* d_ws, size_t ws_size,
                              hipStream_t stream) {
    (void)in_sizes; (void)n_in; (void)d_ws; (void)ws_size; (void)out_size;
    hipFuncSetAttribute((const void*)rnn_fused,
                        hipFuncAttributeMaxDynamicSharedMemorySize, LDS_TOTAL);
    rnn_fused<<<dim3(512), dim3(512), LDS_TOTAL, stream>>>(
        (const float*)d_in[0], (const float*)d_in[1], (const float*)d_in[2],
        (const float*)d_in[3], (const float*)d_in[4], (const float*)d_in[5],
        (const float*)d_in[6], (const float*)d_in[7], (float*)d_out);
}